// Round 1
// baseline (1036.314 us; speedup 1.0000x reference)
//
#include <hip/hip_runtime.h>

#define B 8
#define L 30
#define D 512
#define NS 21
#define NI 8

// ---------- helpers ----------
__device__ __forceinline__ float block_reduce_sum_256(float v, float* red) {
  int lane = threadIdx.x & 63;
  int wid  = threadIdx.x >> 6;
  #pragma unroll
  for (int o = 32; o > 0; o >>= 1) v += __shfl_down(v, o, 64);
  __syncthreads();
  if (lane == 0) red[wid] = v;
  __syncthreads();
  float r = 0.f;
  if (threadIdx.x == 0) {
    #pragma unroll
    for (int w = 0; w < 4; w++) r += red[w];
  }
  return r;  // valid on thread 0 only
}

// ---------- Phase A: per (b,l): a_words, softmax(route logits)->wc, slots ----------
__global__ void k_phase_a(const float* __restrict__ x,
                          const float* __restrict__ w_route_ws,
                          float* __restrict__ wc,
                          float* __restrict__ a_words,
                          float* __restrict__ slots_out) {
  __shared__ float red[4];
  __shared__ float logits[NS];
  __shared__ float s_aw;
  int bl = blockIdx.x;
  int l  = bl % L;
  const float* xv = x + (size_t)bl * D;

  float p = 0.f;
  for (int j = threadIdx.x; j < D; j += 256) p += xv[j];
  float tot = block_reduce_sum_256(p, red);
  if (threadIdx.x == 0) { s_aw = tot / (float)D; a_words[bl] = s_aw; }

  for (int n = 0; n < NS; n++) {
    const float* wr = w_route_ws + (size_t)(l * NS + n) * D;
    float q = 0.f;
    for (int j = threadIdx.x; j < D; j += 256) q += wr[j] * xv[j];
    float t = block_reduce_sum_256(q, red);
    if (threadIdx.x == 0) logits[n] = t;
  }
  __syncthreads();
  if (threadIdx.x == 0) {
    float m = logits[0]; int am = 0;
    #pragma unroll
    for (int n = 1; n < NS; n++) if (logits[n] > m) { m = logits[n]; am = n; }
    float e[NS]; float se = 0.f;
    #pragma unroll
    for (int n = 0; n < NS; n++) { e[n] = __expf(logits[n] - m); se += e[n]; }
    float sc = s_aw / se;  // wc = softmax * a_words
    #pragma unroll
    for (int n = 0; n < NS; n++) wc[(size_t)bl * NS + n] = e[n] * sc;
    slots_out[bl] = (float)am;  // argmax(c_ws) == argmax(logits)
  }
}

// ---------- Stats 1: weighted_c[b,n], a_slots[b,n] ----------
__global__ void k_stats1(const float* __restrict__ wc,
                         const float* __restrict__ a_words,
                         float* __restrict__ weighted_c,
                         float* __restrict__ a_slots) {
  __shared__ float aw_sum[B];
  int t = threadIdx.x;
  if (t < B) {
    float s = 0.f;
    for (int l = 0; l < L; l++) s += a_words[t * L + l];
    aw_sum[t] = s;
  }
  __syncthreads();
  if (t < B * NS) {
    int b = t / NS, n = t % NS;
    float s = 0.f;
    for (int l = 0; l < L; l++) s += wc[(size_t)(b * L + l) * NS + n];
    weighted_c[t] = s;
    a_slots[t] = s / aw_sum[b];
  }
}

// ---------- Phase B (heavy): u_slots[b,n,i] = sum_l wc[b,l,n] * (W_ws[l,n] @ x[b,l]) / weighted_c[b,n]
// block = 256 thr (4 waves); wave handles 4 consecutive i-rows for ALL 8 batches.
// grid = NS * 32 (32 blocks of 16 rows cover D=512 per n).
__global__ void __launch_bounds__(256) k_u_slots(
    const float* __restrict__ x,
    const float* __restrict__ w_pose_ws,
    const float* __restrict__ wc,
    const float* __restrict__ weighted_c,
    float* __restrict__ u_slots) {
  __shared__ float lwc[B * L];  // wc[b,l,n] for this block's n
  __shared__ float lwcn[B];     // weighted_c[b,n]
  int n     = blockIdx.x >> 5;
  int itile = blockIdx.x & 31;
  int wave  = threadIdx.x >> 6;
  int lane  = threadIdx.x & 63;
  int i0    = itile * 16 + wave * 4;

  if (threadIdx.x < B * L) lwc[threadIdx.x] = wc[(size_t)threadIdx.x * NS + n];
  if (threadIdx.x >= 240 && threadIdx.x < 240 + B)
    lwcn[threadIdx.x - 240] = weighted_c[(threadIdx.x - 240) * NS + n];
  __syncthreads();

  float acc[4][B];
  #pragma unroll
  for (int r = 0; r < 4; r++)
    #pragma unroll
    for (int b = 0; b < B; b++) acc[r][b] = 0.f;

  for (int l = 0; l < L; l++) {
    const float* wrow = w_pose_ws + ((size_t)(l * NS + n) * D + i0) * D;
    float4 w0[4], w1[4];
    #pragma unroll
    for (int r = 0; r < 4; r++) {
      const float4* wp = (const float4*)(wrow + (size_t)r * D) + lane * 2;
      w0[r] = wp[0]; w1[r] = wp[1];
    }
    #pragma unroll
    for (int b = 0; b < B; b++) {
      const float4* xp = (const float4*)(x + (size_t)(b * L + l) * D) + lane * 2;
      float4 x0 = xp[0], x1 = xp[1];
      float wcl = lwc[b * L + l];
      #pragma unroll
      for (int r = 0; r < 4; r++) {
        float t = w0[r].x * x0.x + w0[r].y * x0.y + w0[r].z * x0.z + w0[r].w * x0.w
                + w1[r].x * x1.x + w1[r].y * x1.y + w1[r].z * x1.z + w1[r].w * x1.w;
        acc[r][b] += wcl * t;
      }
    }
  }
  #pragma unroll
  for (int r = 0; r < 4; r++)
    #pragma unroll
    for (int b = 0; b < B; b++)
      #pragma unroll
      for (int o = 32; o > 0; o >>= 1) acc[r][b] += __shfl_xor(acc[r][b], o, 64);
  if (lane == 0) {
    #pragma unroll
    for (int r = 0; r < 4; r++)
      #pragma unroll
      for (int b = 0; b < B; b++)
        u_slots[((size_t)b * NS + n) * D + (i0 + r)] = acc[r][b] / lwcn[b];
  }
}

// ---------- Phase C: per (b,s): softmax over NI of route_si logits -> wc2 ----------
__global__ void k_route_si(const float* __restrict__ u_slots,
                           const float* __restrict__ w_route_si,
                           const float* __restrict__ a_slots,
                           float* __restrict__ wc2) {
  __shared__ float red[4];
  __shared__ float logits[NI];
  int bs = blockIdx.x;  // = b*NS + s
  int s  = bs % NS;
  const float* uv = u_slots + (size_t)bs * D;
  for (int i = 0; i < NI; i++) {
    const float* wr = w_route_si + (size_t)(s * NI + i) * D;
    float q = 0.f;
    for (int j = threadIdx.x; j < D; j += 256) q += wr[j] * uv[j];
    float t = block_reduce_sum_256(q, red);
    if (threadIdx.x == 0) logits[i] = t;
  }
  __syncthreads();
  if (threadIdx.x == 0) {
    float m = logits[0];
    #pragma unroll
    for (int i = 1; i < NI; i++) m = fmaxf(m, logits[i]);
    float e[NI]; float se = 0.f;
    #pragma unroll
    for (int i = 0; i < NI; i++) { e[i] = __expf(logits[i] - m); se += e[i]; }
    float sc = a_slots[bs] / se;
    #pragma unroll
    for (int i = 0; i < NI; i++) wc2[(size_t)bs * NI + i] = e[i] * sc;
  }
}

// ---------- Stats 2: weighted_c2[b,i], a_intents, max_idx[b] ----------
__global__ void k_stats2(const float* __restrict__ wc2,
                         const float* __restrict__ a_slots,
                         float* __restrict__ weighted_c2,
                         int* __restrict__ max_idx) {
  __shared__ float asum[B];
  __shared__ float ai[B * NI];
  int t = threadIdx.x;
  if (t < B) {
    float s = 0.f;
    for (int n = 0; n < NS; n++) s += a_slots[t * NS + n];
    asum[t] = s;
  }
  float w = 0.f;
  if (t < B * NI) {
    int b = t / NI, i = t % NI;
    for (int ss = 0; ss < NS; ss++) w += wc2[(size_t)(b * NS + ss) * NI + i];
    weighted_c2[t] = w;
  }
  __syncthreads();
  if (t < B * NI) ai[t] = w / asum[t / NI];
  __syncthreads();
  if (t < B) {
    float m = ai[t * NI]; int am = 0;
    #pragma unroll
    for (int i = 1; i < NI; i++) { float v = ai[t * NI + i]; if (v > m) { m = v; am = i; } }
    max_idx[t] = am;
  }
}

// ---------- Phase D (fused, argmax-only): note reference einsum 'sijk,bsk->bsik'
// contracts j (dim 2) elementwise in k: u_hat[b,s,i,k] = u_slots[b,s,k] * sum_j Wsi[s,i,j,k].
// Only i = max_idx[b] is ever consumed, so compute column-sums just for that column.
__global__ void k_pose_si(const float* __restrict__ w_pose_si,
                          const float* __restrict__ u_slots,
                          const float* __restrict__ wc2,
                          const int* __restrict__ max_idx,
                          float* __restrict__ poses) {
  const int JS = 4;
  int idx = blockIdx.x;                 // b*NS*JS + s*JS + jc
  int b   = idx / (NS * JS);
  int rem = idx - b * (NS * JS);
  int s   = rem / JS, jc = rem % JS;
  int i   = max_idx[b];
  int k   = threadIdx.x;                // 512 threads
  const float* wb = w_pose_si + (size_t)(s * NI + i) * D * D + k;
  float cs = 0.f;
  int j0 = jc * (D / JS);
  #pragma unroll 8
  for (int j = j0; j < j0 + D / JS; j++) cs += wb[(size_t)j * D];
  float val = wc2[(size_t)(b * NS + s) * NI + i] *
              u_slots[(size_t)(b * NS + s) * D + k] * cs;
  atomicAdd(&poses[b * D + k], val);
}

// ---------- Final: intents = cls + poses / weighted_c2[b, i*] ----------
__global__ void k_final(const float* __restrict__ cls,
                        const float* __restrict__ poses,
                        const float* __restrict__ weighted_c2,
                        const int* __restrict__ max_idx,
                        float* __restrict__ out_intents) {
  int b = blockIdx.x, k = threadIdx.x;
  out_intents[b * D + k] =
      cls[b * D + k] + poses[b * D + k] / weighted_c2[b * NI + max_idx[b]];
}

extern "C" void kernel_launch(void* const* d_in, const int* in_sizes, int n_in,
                              void* d_out, int out_size, void* d_ws, size_t ws_size,
                              hipStream_t stream) {
  const float* x    = (const float*)d_in[0];  // (B,L,D)
  const float* cls  = (const float*)d_in[1];  // (B,D)
  const float* wrws = (const float*)d_in[2];  // (L,NS,D)
  const float* wpws = (const float*)d_in[3];  // (L,NS,D,D)
  const float* wrsi = (const float*)d_in[4];  // (NS,NI,D)
  const float* wpsi = (const float*)d_in[5];  // (NS,NI,D,D)

  float* out         = (float*)d_out;
  float* slots_out   = out;           // B*L = 240 (ints as float)
  float* intents_out = out + B * L;   // B*D = 4096

  float* wsf         = (float*)d_ws;
  float* wc          = wsf;                    // B*L*NS = 5040
  float* a_words     = wc + B * L * NS;        // 240
  float* weighted_c  = a_words + B * L;        // B*NS = 168
  float* a_slots     = weighted_c + B * NS;    // 168
  float* u_slots     = a_slots + B * NS;       // B*NS*D = 86016
  float* wc2         = u_slots + B * NS * D;   // B*NS*NI = 1344
  float* weighted_c2 = wc2 + B * NS * NI;      // B*NI = 64
  float* poses       = weighted_c2 + B * NI;   // B*D = 4096
  int*   max_idx     = (int*)(poses + B * D);  // 8

  hipMemsetAsync(poses, 0, B * D * sizeof(float), stream);
  k_phase_a<<<B * L, 256, 0, stream>>>(x, wrws, wc, a_words, slots_out);
  k_stats1<<<1, 256, 0, stream>>>(wc, a_words, weighted_c, a_slots);
  k_u_slots<<<NS * 32, 256, 0, stream>>>(x, wpws, wc, weighted_c, u_slots);
  k_route_si<<<B * NS, 256, 0, stream>>>(u_slots, wrsi, a_slots, wc2);
  k_stats2<<<1, 256, 0, stream>>>(wc2, a_slots, weighted_c2, max_idx);
  k_pose_si<<<B * NS * 4, 512, 0, stream>>>(wpsi, u_slots, wc2, max_idx, poses);
  k_final<<<B, 512, 0, stream>>>(cls, poses, weighted_c2, max_idx, intents_out);
}